// Round 5
// baseline (243.350 us; speedup 1.0000x reference)
//
#include <hip/hip_runtime.h>
#include <hip/hip_bf16.h>
#include <stdint.h>

#define N_   64
#define L_   1024
#define D_   512
#define S_   127
#define OUT_ 300
#define NT_  20            // col-tiles of 16 -> 320 padded cols
#define EPS_ 1e-5f
#define M_TOTAL (N_*S_)    // 8128
#define NBLK (M_TOTAL/16)  // 508 blocks, 16 rows each
#define AST  520           // A LDS row stride (bf16): 1040B, 16B-aligned
#define HSTR 325           // epilogue h stride (floats): depads banks

typedef __attribute__((ext_vector_type(4))) float  float4v;
typedef __attribute__((ext_vector_type(8))) __bf16 bf16x8;
typedef __attribute__((ext_vector_type(4))) __bf16 bf16x4;

// Single fused kernel: use-copy + cooperative span-means -> LDS (1 barrier)
// -> MFMA with B converted f32->bf16 in-register from L2-hot w_lin -> LayerNorm.
__global__ __launch_bounds__(256) void enc_all(
    const float* __restrict__ t1, const int* __restrict__ wseq,
    const float* __restrict__ w_lin, const float* __restrict__ b_lin,
    const float* __restrict__ gamma, const float* __restrict__ beta,
    float* __restrict__ out)
{
    __shared__ __align__(16) char smem[16 * HSTR * 4];   // 20800B; A-tile aliased with h
    __bf16* Alds = (__bf16*)smem;                        // [16][520]
    float*  hlds = (float*)smem;                         // [16][325]

    const int tid  = threadIdx.x;
    const int blk  = blockIdx.x;
    const int lane = tid & 63;
    const int wave = tid >> 6;
    const int quad = lane >> 4;
    const int ln16 = lane & 15;

    // ---- use = t1[:,0,:] folded into blocks 0..31 (one float4 per thread)
    if (blk < 32) {
        int idx = blk * 256 + tid;                       // 8192 float4s
        int n = idx >> 7, dg = idx & 127;
        float4v v = *(const float4v*)(t1 + (size_t)n * L_ * D_ + dg * 4);
        *(float4v*)(out + (size_t)M_TOTAL * OUT_ + n * D_ + dg * 4) = v;
    }

    // ---- A-stage: full 16x512 mean tile, all 256 threads, one load burst
    {
        const int row = tid >> 4;          // 0..15
        const int kg  = tid & 15;          // float4 group base
        const int m   = blk * 16 + row;
        const int st  = min(wseq[2 * m],     L_ - 3);   // min(start, li-1), li=1022
        const int en  = min(wseq[2 * m + 1], L_ - 2);   // min(end, li)
        const int cnt = en - st;
        const float inv_cnt = 1.0f / (float)cnt;
        const int nn = m / S_;
        const float* base = t1 + ((size_t)nn * L_ + 1 + st) * D_ + kg * 4;
        #pragma unroll
        for (int c = 0; c < 8; ++c) {
            const int k0 = c * 64;
            float4v s = {0.f, 0.f, 0.f, 0.f};
            if (cnt == 8) {                // fast path (true for this data)
                #pragma unroll
                for (int j = 0; j < 8; ++j) s += *(const float4v*)(base + j * D_ + k0);
            } else {
                for (int j = 0; j < cnt; ++j) s += *(const float4v*)(base + j * D_ + k0);
            }
            s *= inv_cnt;
            bf16x4 a4;
            a4[0]=(__bf16)s[0]; a4[1]=(__bf16)s[1]; a4[2]=(__bf16)s[2]; a4[3]=(__bf16)s[3];
            *(bf16x4*)(Alds + row * AST + k0 + kg * 4) = a4;
        }
    }
    __syncthreads();

    // ---- GEMM: wave owns 5 col-tiles; B-frags loaded f32 from w_lin (L2-hot),
    // converted to bf16 in-register. Lanes (quad 0-3, same ln16) cover one full
    // 128B line per weight row -> 100% line utilization.
    float4v acc[5];
    #pragma unroll
    for (int i = 0; i < 5; ++i) acc[i] = float4v{0.f, 0.f, 0.f, 0.f};
    const int t0 = wave * 5;

    const float* wbase[5];
    float osc[5];
    #pragma unroll
    for (int i = 0; i < 5; ++i) {
        int o = (t0 + i) * 16 + ln16;
        osc[i]   = (o < OUT_) ? 1.0f : 0.0f;             // padded cols -> zero B
        wbase[i] = w_lin + (size_t)min(o, OUT_ - 1) * D_ + quad * 8;
    }

    #pragma unroll 2
    for (int kt = 0; kt < 8; ++kt) {
        bf16x8 af0 = *(const bf16x8*)(Alds + ln16 * AST + kt * 64 + quad * 8);
        bf16x8 af1 = *(const bf16x8*)(Alds + ln16 * AST + kt * 64 + 32 + quad * 8);
        #pragma unroll
        for (int i = 0; i < 5; ++i) {
            const float* p = wbase[i] + kt * 64;
            const float sc = osc[i];
            float4v f0 = *(const float4v*)(p);          // ks=0: k = kt*64+quad*8+0..8
            float4v f1 = *(const float4v*)(p + 4);
            bf16x8 b0;
            b0[0]=(__bf16)(f0[0]*sc); b0[1]=(__bf16)(f0[1]*sc);
            b0[2]=(__bf16)(f0[2]*sc); b0[3]=(__bf16)(f0[3]*sc);
            b0[4]=(__bf16)(f1[0]*sc); b0[5]=(__bf16)(f1[1]*sc);
            b0[6]=(__bf16)(f1[2]*sc); b0[7]=(__bf16)(f1[3]*sc);
            acc[i] = __builtin_amdgcn_mfma_f32_16x16x32_bf16(af0, b0, acc[i], 0, 0, 0);
            float4v g0 = *(const float4v*)(p + 32);     // ks=1: k = kt*64+32+quad*8+0..8
            float4v g1 = *(const float4v*)(p + 36);
            bf16x8 b1;
            b1[0]=(__bf16)(g0[0]*sc); b1[1]=(__bf16)(g0[1]*sc);
            b1[2]=(__bf16)(g0[2]*sc); b1[3]=(__bf16)(g0[3]*sc);
            b1[4]=(__bf16)(g1[0]*sc); b1[5]=(__bf16)(g1[1]*sc);
            b1[6]=(__bf16)(g1[2]*sc); b1[7]=(__bf16)(g1[3]*sc);
            acc[i] = __builtin_amdgcn_mfma_f32_16x16x32_bf16(af1, b1, acc[i], 0, 0, 0);
        }
    }
    __syncthreads();   // all A reads done; reuse LDS for h

    // ---- epilogue: h = acc + b_lin -> LDS (C layout: row = quad*4+r, col = t*16+ln16)
    #pragma unroll
    for (int i = 0; i < 5; ++i) {
        const int col = (t0 + i) * 16 + ln16;
        const float bl = (col < OUT_) ? b_lin[col] : 0.0f;
        #pragma unroll
        for (int r = 0; r < 4; ++r)
            hlds[(quad * 4 + r) * HSTR + col] = acc[i][r] + bl;
    }
    __syncthreads();

    // ---- LayerNorm over 300 cols; 16 threads per row
    const int r  = tid >> 4;
    const int c0 = tid & 15;
    float sum = 0.f, sq = 0.f;
    #pragma unroll
    for (int i = 0; i < 19; ++i) {
        int c = c0 + 16 * i;
        if (c < OUT_) { float v = hlds[r * HSTR + c]; sum += v; sq += v * v; }
    }
    #pragma unroll
    for (int off = 8; off > 0; off >>= 1) {
        sum += __shfl_xor(sum, off);
        sq  += __shfl_xor(sq,  off);
    }
    const float mu  = sum * (1.0f / OUT_);
    const float var = sq * (1.0f / OUT_) - mu * mu;
    const float rs  = rsqrtf(var + EPS_);
    float* orow = out + (size_t)(blk * 16 + r) * OUT_;
    #pragma unroll
    for (int i = 0; i < 19; ++i) {
        int c = c0 + 16 * i;
        if (c < OUT_) {
            float v = hlds[r * HSTR + c];
            orow[c] = (v - mu) * rs * gamma[c] + beta[c];
        }
    }
}

extern "C" void kernel_launch(void* const* d_in, const int* in_sizes, int n_in,
                              void* d_out, int out_size, void* d_ws, size_t ws_size,
                              hipStream_t stream) {
    const float* t1    = (const float*)d_in[0];
    const int*   wseq  = (const int*)d_in[1];   // word_seq (int32); d_in[2] mask unused
    const float* w_lin = (const float*)d_in[3];
    const float* b_lin = (const float*)d_in[4];
    const float* gamma = (const float*)d_in[5];
    const float* beta  = (const float*)d_in[6];
    float* out = (float*)d_out;

    enc_all<<<NBLK, 256, 0, stream>>>(t1, wseq, w_lin, b_lin, gamma, beta, out);
}

// Round 6
// 215.409 us; speedup vs baseline: 1.1297x; 1.1297x over previous
//
#include <hip/hip_runtime.h>
#include <hip/hip_bf16.h>
#include <stdint.h>

#define N_   64
#define L_   1024
#define D_   512
#define S_   127
#define OUT_ 300
#define NT_  20              // col-tiles of 16 -> 320 padded cols
#define EPS_ 1e-5f
#define M_TOTAL (N_*S_)      // 8128
#define GBLK (M_TOTAL/16)    // 508 GEMM blocks, 16 rows each
#define MEANS_BLOCKS 4064    // M_TOTAL*128/256
#define USE_BLOCKS   32      // N_*D_/4/256
#define PACK_BLOCKS  80      // NT_*1024/256
#define HSTR 325             // epilogue h stride (floats): depads banks
#define MEANS_OFF 524288     // byte offset of means in d_ws (wpk is 327680B at 0)

typedef __attribute__((ext_vector_type(4))) float  float4v;
typedef __attribute__((ext_vector_type(8))) __bf16 bf16x8;
typedef __attribute__((ext_vector_type(4))) __bf16 bf16x4;

// ---- prep: span-means (streaming, full BW) + use-copy + weight pack, one launch ----
// wpk elem layout: [t(20)][kt(8)][ks(2)][lane(64)][j(8)] -> wave B-load = 1KB contiguous.
__global__ __launch_bounds__(256) void prep_means(
    const float* __restrict__ t1, const int* __restrict__ wseq,
    const float* __restrict__ w, __bf16* __restrict__ wpk,
    __bf16* __restrict__ means, float* __restrict__ ouse)
{
    const int blk = blockIdx.x, tid = threadIdx.x;
    if (blk < MEANS_BLOCKS) {
        // span means: one thread per (m, float4-group); reads t1 exactly once
        int idx = blk * 256 + tid;
        int m  = idx >> 7;                           // 0..8127
        int dg = idx & 127;
        int st = min(wseq[2 * m],     L_ - 3);       // min(start, li-1), li=1022
        int en = min(wseq[2 * m + 1], L_ - 2);       // min(end, li)
        int cnt = en - st;
        int n = m / S_;
        const float* base = t1 + ((size_t)n * L_ + 1 + st) * D_ + dg * 4;
        float4v s = {0.f, 0.f, 0.f, 0.f};
        if (cnt == 8) {                              // fast path (true for this data)
            #pragma unroll
            for (int j = 0; j < 8; ++j) s += *(const float4v*)(base + j * D_);
        } else {
            for (int j = 0; j < cnt; ++j) s += *(const float4v*)(base + j * D_);
        }
        s *= (1.0f / (float)cnt);
        bf16x4 a4;
        a4[0]=(__bf16)s[0]; a4[1]=(__bf16)s[1]; a4[2]=(__bf16)s[2]; a4[3]=(__bf16)s[3];
        *(bf16x4*)(means + (size_t)m * D_ + dg * 4) = a4;
    } else if (blk < MEANS_BLOCKS + USE_BLOCKS) {
        // use = t1[:,0,:]
        int idx = (blk - MEANS_BLOCKS) * 256 + tid;  // 8192 float4s
        int n = idx >> 7, dg = idx & 127;
        float4v v = *(const float4v*)(t1 + (size_t)n * L_ * D_ + dg * 4);
        *(float4v*)(ouse + n * D_ + dg * 4) = v;
    } else {
        // pack w_lin f32->bf16 into MFMA B-fragment order (padded rows -> 0)
        int idx = (blk - MEANS_BLOCKS - USE_BLOCKS) * 256 + tid;  // 20480 chunks
        int t    = idx >> 10;
        int kt   = (idx >> 7) & 7;
        int ks   = (idx >> 6) & 1;
        int quad = (idx >> 4) & 3;
        int l16  = idx & 15;
        int o  = t * 16 + l16;
        int k0 = kt * 64 + ks * 32 + quad * 8;
        bf16x8 v;
        if (o < OUT_) {
            float4v f0 = *(const float4v*)(w + o * D_ + k0);
            float4v f1 = *(const float4v*)(w + o * D_ + k0 + 4);
            v[0]=(__bf16)f0[0]; v[1]=(__bf16)f0[1]; v[2]=(__bf16)f0[2]; v[3]=(__bf16)f0[3];
            v[4]=(__bf16)f1[0]; v[5]=(__bf16)f1[1]; v[6]=(__bf16)f1[2]; v[7]=(__bf16)f1[3];
        } else {
            #pragma unroll
            for (int j = 0; j < 8; ++j) v[j] = (__bf16)0.0f;
        }
        *(bf16x8*)(wpk + (size_t)idx * 8) = v;
    }
}

// ---- GEMM + LayerNorm: no staging, all fragments direct from cache-hot global ----
__global__ __launch_bounds__(256, 2) void gemm_ln(
    const __bf16* __restrict__ means, const __bf16* __restrict__ wpk,
    const float* __restrict__ b_lin, const float* __restrict__ gamma,
    const float* __restrict__ beta, float* __restrict__ out)
{
    __shared__ __align__(16) float hlds[16 * HSTR];   // 20800 B, epilogue only

    const int tid  = threadIdx.x;
    const int blk  = blockIdx.x;
    const int lane = tid & 63;
    const int wave = tid >> 6;
    const int quad = lane >> 4;
    const int ln16 = lane & 15;
    const int m0   = blk * 16;

    // A-fragments for full K, straight from means (L2/L3-hot): 16 independent loads
    const __bf16* ab = means + (size_t)(m0 + ln16) * D_ + quad * 8;
    bf16x8 A0[8], A1[8];
    #pragma unroll
    for (int kt = 0; kt < 8; ++kt) {
        A0[kt] = *(const bf16x8*)(ab + kt * 64);
        A1[kt] = *(const bf16x8*)(ab + kt * 64 + 32);
    }

    float4v acc[5];
    #pragma unroll
    for (int i = 0; i < 5; ++i) acc[i] = float4v{0.f, 0.f, 0.f, 0.f};
    const int t0 = wave * 5;

    // fully unrolled K-loop: 80 independent bf16x8 B-loads (L2-hot), no barriers
    #pragma unroll
    for (int kt = 0; kt < 8; ++kt) {
        const __bf16* bp = wpk + ((size_t)kt * 128 + lane) * 8;
        #pragma unroll
        for (int i = 0; i < 5; ++i) {
            const __bf16* bt = bp + (size_t)(t0 + i) * 8192;
            bf16x8 b0 = *(const bf16x8*)(bt);          // ks=0
            bf16x8 b1 = *(const bf16x8*)(bt + 512);    // ks=1
            acc[i] = __builtin_amdgcn_mfma_f32_16x16x32_bf16(A0[kt], b0, acc[i], 0, 0, 0);
            acc[i] = __builtin_amdgcn_mfma_f32_16x16x32_bf16(A1[kt], b1, acc[i], 0, 0, 0);
        }
    }

    // epilogue: h = acc + b_lin -> LDS (C layout: row = quad*4+r, col = t*16+ln16)
    #pragma unroll
    for (int i = 0; i < 5; ++i) {
        const int col = (t0 + i) * 16 + ln16;
        const float bl = (col < OUT_) ? b_lin[col] : 0.0f;
        #pragma unroll
        for (int r = 0; r < 4; ++r)
            hlds[(quad * 4 + r) * HSTR + col] = acc[i][r] + bl;
    }
    __syncthreads();

    // LayerNorm over 300 cols; 16 threads per row
    const int r  = tid >> 4;
    const int c0 = tid & 15;
    float sum = 0.f, sq = 0.f;
    #pragma unroll
    for (int i = 0; i < 19; ++i) {
        int c = c0 + 16 * i;
        if (c < OUT_) { float v = hlds[r * HSTR + c]; sum += v; sq += v * v; }
    }
    #pragma unroll
    for (int off = 8; off > 0; off >>= 1) {
        sum += __shfl_xor(sum, off);
        sq  += __shfl_xor(sq,  off);
    }
    const float mu  = sum * (1.0f / OUT_);
    const float var = sq * (1.0f / OUT_) - mu * mu;
    const float rs  = rsqrtf(var + EPS_);
    float* orow = out + (size_t)(m0 + r) * OUT_;
    #pragma unroll
    for (int i = 0; i < 19; ++i) {
        int c = c0 + 16 * i;
        if (c < OUT_) {
            float v = hlds[r * HSTR + c];
            orow[c] = (v - mu) * rs * gamma[c] + beta[c];
        }
    }
}

extern "C" void kernel_launch(void* const* d_in, const int* in_sizes, int n_in,
                              void* d_out, int out_size, void* d_ws, size_t ws_size,
                              hipStream_t stream) {
    const float* t1    = (const float*)d_in[0];
    const int*   wseq  = (const int*)d_in[1];   // word_seq (int32); d_in[2] mask unused
    const float* w_lin = (const float*)d_in[3];
    const float* b_lin = (const float*)d_in[4];
    const float* gamma = (const float*)d_in[5];
    const float* beta  = (const float*)d_in[6];
    float* out  = (float*)d_out;
    __bf16* wpk   = (__bf16*)d_ws;                       // 327680 B at offset 0
    __bf16* means = (__bf16*)((char*)d_ws + MEANS_OFF);  // 8.32 MB

    prep_means<<<MEANS_BLOCKS + USE_BLOCKS + PACK_BLOCKS, 256, 0, stream>>>(
        t1, wseq, w_lin, wpk, means, out + (size_t)M_TOTAL * OUT_);
    gemm_ln<<<GBLK, 256, 0, stream>>>(means, wpk, b_lin, gamma, beta, out);
}